// Round 3
// baseline (48298.734 us; speedup 1.0000x reference)
//
#include <hip/hip_runtime.h>
#include <math.h>

#define NT 4096      // n_train
#define MT 8192      // n_test
#define NB 128       // cholesky block
#define NBLK 32      // NT/NB
#define TBM 128      // gemm tile M
#define TBN 64       // gemm tile N
#define TBK 32       // gemm tile K

// ---------------- helpers ----------------
__device__ __forceinline__ float bf2f(unsigned short h) {
  return __uint_as_float(((unsigned)h) << 16);
}
__device__ __forceinline__ float softplusf(float x) { return log1pf(expf(x)); }

__device__ __forceinline__ void load8bf(const unsigned short* __restrict__ p, float* f) {
  ushort4 u0 = *(const ushort4*)p;
  ushort4 u1 = *(const ushort4*)(p + 4);
  f[0] = bf2f(u0.x); f[1] = bf2f(u0.y); f[2] = bf2f(u0.z); f[3] = bf2f(u0.w);
  f[4] = bf2f(u1.x); f[5] = bf2f(u1.y); f[6] = bf2f(u1.z); f[7] = bf2f(u1.w);
}

// dtype-polymorphic input readers (flag: 1 = f32 inputs, 0 = bf16 inputs)
__device__ __forceinline__ float getsc(const void* p, int f32) {
  return f32 ? *(const float*)p : bf2f(*(const unsigned short*)p);
}
__device__ __forceinline__ float getel(const void* p, int i, int f32) {
  return f32 ? ((const float*)p)[i] : bf2f(((const unsigned short*)p)[i]);
}
__device__ __forceinline__ void load_pt(const void* xb, int idx, int f32, float* f) {
  if (f32) {
    const float4* q = (const float4*)xb;
    float4 a = q[idx * 2], b = q[idx * 2 + 1];
    f[0] = a.x; f[1] = a.y; f[2] = a.z; f[3] = a.w;
    f[4] = b.x; f[5] = b.y; f[6] = b.z; f[7] = b.w;
  } else {
    load8bf((const unsigned short*)xb + idx * 8, f);
  }
}

// uniform-[0,1) bf16 ushorts are all < 0x4000; f32 low mantissa halves are ~random
__global__ void detect_dtype(const unsigned short* __restrict__ xt, int* __restrict__ flag) {
  if (threadIdx.x == 0) {
    int f = 0;
    for (int i = 0; i < 32; i++) if (xt[i] >= 0x4000) f = 1;
    flag[0] = f;
  }
}

// ---------------- kernel-matrix builders (-> f32 out) ----------------
__global__ void build_K(const void* __restrict__ xt, const void* __restrict__ w,
                        const void* __restrict__ rls, const void* __restrict__ rvar,
                        const void* __restrict__ rnv, float* __restrict__ K,
                        const int* __restrict__ flag) {
  int f32 = flag[0];
  int j = blockIdx.x * 16 + threadIdx.x;
  int i = blockIdx.y * 16 + threadIdx.y;
  float ls  = softplusf(getsc(rls, f32));
  float var = softplusf(getsc(rvar, f32));
  float cc  = -0.5f / (ls * ls);
  float v;
  if (i == j) {
    v = var + softplusf(getsc(rnv, f32)) + 1e-6f;      // rbf diag = var, + noise
  } else {
    float a[8], b[8];
    load_pt(xt, i, f32, a);
    load_pt(xt, j, f32, b);
    float d = 0.f;
#pragma unroll
    for (int q = 0; q < 8; q++) { float t = a[q] - b[q]; d += t * t; }
    v = var * expf(cc * d) * getel(w, i, f32) * getel(w, j, f32);
  }
  K[(size_t)i * NT + j] = v;
}

__global__ void build_Ks(const void* __restrict__ xt, const void* __restrict__ xs,
                         const void* __restrict__ w, const void* __restrict__ rls,
                         const void* __restrict__ rvar, float* __restrict__ Ks,
                         const int* __restrict__ flag) {
  int f32 = flag[0];
  int j = blockIdx.x * 16 + threadIdx.x;   // test
  int i = blockIdx.y * 16 + threadIdx.y;   // train
  float ls  = softplusf(getsc(rls, f32));
  float var = softplusf(getsc(rvar, f32));
  float cc  = -0.5f / (ls * ls);
  float a[8], b[8];
  load_pt(xt, i, f32, a);
  load_pt(xs, j, f32, b);
  float d = 0.f;
#pragma unroll
  for (int q = 0; q < 8; q++) { float t = a[q] - b[q]; d += t * t; }
  Ks[(size_t)i * MT + j] = getel(w, i, f32) * var * expf(cc * d);
}

// ---------------- diagonal-block Cholesky (1 workgroup) ----------------
__global__ void __launch_bounds__(256) potrf_diag(float* __restrict__ Kg, int kb) {
  __shared__ float At[NB * NB];   // 64 KB, column-major (block symmetric)
  int tid = threadIdx.x;
  int r0 = kb * NB;
  for (int idx = tid; idx < NB * NB; idx += 256) {
    int k = idx >> 7, i = idx & 127;
    At[idx] = Kg[(size_t)(r0 + k) * NT + r0 + i];
  }
  __syncthreads();
  for (int j = 0; j < NB; j++) {
    float inv = 1.0f / At[j * NB + j];
    int nel = (NB - 1 - j) << 7;
    for (int idx = tid; idx < nel; idx += 256) {
      int k = j + 1 + (idx >> 7);
      int i = idx & 127;
      if (i >= k) At[k * NB + i] -= At[j * NB + i] * (At[j * NB + k] * inv);
    }
    __syncthreads();
  }
  for (int idx = tid; idx < NB * NB; idx += 256) {
    int k = idx >> 7, i = idx & 127;
    if (i >= k) {
      float s = sqrtf(At[k * NB + k]);
      float v = (i == k) ? s : At[idx] / s;
      Kg[(size_t)(r0 + i) * NT + r0 + k] = v;
    }
  }
}

// W = Lkk^{-1} via forward elimination of I
__global__ void __launch_bounds__(256) invert_diag(const float* __restrict__ Kg,
                                                   float* __restrict__ Wall, int kb) {
  __shared__ float Wv[NB * NB];   // 64 KB, row-major
  int tid = threadIdx.x;
  int r0 = kb * NB;
  for (int idx = tid; idx < NB * NB; idx += 256) {
    int i = idx >> 7, c = idx & 127;
    Wv[idx] = (i == c) ? 1.f : 0.f;
  }
  __syncthreads();
  for (int t = 0; t < NB; t++) {
    float invd = 1.0f / Kg[(size_t)(r0 + t) * NT + r0 + t];
    int nel = (NB - 1 - t) << 7;
    for (int idx = tid; idx < nel; idx += 256) {
      int i = t + 1 + (idx >> 7);
      int c = idx & 127;
      float lit = Kg[(size_t)(r0 + i) * NT + r0 + t];
      Wv[i * NB + c] -= lit * (Wv[t * NB + c] * invd);
    }
    __syncthreads();
  }
  float* Wg = Wall + (size_t)kb * NB * NB;
  for (int idx = tid; idx < NB * NB; idx += 256) {
    int i = idx >> 7;
    float invd = 1.0f / Kg[(size_t)(r0 + i) * NT + r0 + i];
    Wg[idx] = Wv[idx] * invd;
  }
}

__global__ void copy_panel(const float* __restrict__ Kg, float* __restrict__ S,
                           int t0, int rows, int kb) {
  int idx = blockIdx.x * 256 + threadIdx.x;
  if (idx < rows * NB) {
    int r = idx >> 7, c = idx & 127;
    S[idx] = Kg[(size_t)(t0 + r) * NT + kb * NB + c];
  }
}

// ---------------- f32 GEMM tiles: 128x64x32, 256 thr, 8x4 regs ----------------
template<int SUB>
__global__ void __launch_bounds__(256) gemm_nn(const float* __restrict__ A, int lda,
                                               const float* __restrict__ B, int ldb,
                                               float* __restrict__ C, int ldc, int Kdim) {
  __shared__ float As[TBK][TBM + 4];
  __shared__ float Bs[TBK][TBN + 4];
  int tid = threadIdx.x;
  int c0 = blockIdx.x * TBN;
  int r0 = blockIdx.y * TBM;
  int tx = tid & 15, ty = tid >> 4;
  float acc[8][4];
#pragma unroll
  for (int r = 0; r < 8; r++)
#pragma unroll
    for (int c = 0; c < 4; c++) acc[r][c] = 0.f;

  int am = tid & 127, ah = tid >> 7;
  int bn = tid & 15,  bk = tid >> 4;

  for (int kt = 0; kt < Kdim; kt += TBK) {
#pragma unroll
    for (int q = 0; q < 4; q++) {
      int s = ah * 4 + q;
      float4 v = *(const float4*)&A[(size_t)(r0 + am) * lda + kt + s * 4];
      As[s * 4 + 0][am] = v.x; As[s * 4 + 1][am] = v.y;
      As[s * 4 + 2][am] = v.z; As[s * 4 + 3][am] = v.w;
    }
#pragma unroll
    for (int p = 0; p < 2; p++) {
      int kk = bk + p * 16;
      *(float4*)&Bs[kk][bn * 4] = *(const float4*)&B[(size_t)(kt + kk) * ldb + c0 + bn * 4];
    }
    __syncthreads();
#pragma unroll
    for (int k = 0; k < TBK; k++) {
      float a[8], b[4];
      *(float4*)&a[0] = *(const float4*)&As[k][ty * 8];
      *(float4*)&a[4] = *(const float4*)&As[k][ty * 8 + 4];
      *(float4*)&b[0] = *(const float4*)&Bs[k][tx * 4];
#pragma unroll
      for (int r = 0; r < 8; r++)
#pragma unroll
        for (int c = 0; c < 4; c++) acc[r][c] += a[r] * b[c];
    }
    __syncthreads();
  }
#pragma unroll
  for (int r = 0; r < 8; r++) {
    float* cp = &C[(size_t)(r0 + ty * 8 + r) * ldc + c0 + tx * 4];
    if (SUB) {
      float4 o = *(const float4*)cp;
      o.x -= acc[r][0]; o.y -= acc[r][1]; o.z -= acc[r][2]; o.w -= acc[r][3];
      *(float4*)cp = o;
    } else {
      float4 o; o.x = acc[r][0]; o.y = acc[r][1]; o.z = acc[r][2]; o.w = acc[r][3];
      *(float4*)cp = o;
    }
  }
}

// NT: C (op)= A[M x K] @ B[N x K]^T  (SYRK=1: skip tiles fully above diagonal)
template<int SUB, int SYRK>
__global__ void __launch_bounds__(256) gemm_nt(const float* __restrict__ A, int lda,
                                               const float* __restrict__ B, int ldb,
                                               float* __restrict__ C, int ldc, int Kdim) {
  int c0 = blockIdx.x * TBN;
  int r0 = blockIdx.y * TBM;
  if (SYRK && c0 > r0 + TBM - 1) return;
  __shared__ float As[TBK][TBM + 4];
  __shared__ float Bs[TBK][TBN + 4];
  int tid = threadIdx.x;
  int tx = tid & 15, ty = tid >> 4;
  float acc[8][4];
#pragma unroll
  for (int r = 0; r < 8; r++)
#pragma unroll
    for (int c = 0; c < 4; c++) acc[r][c] = 0.f;

  int am = tid & 127, ah = tid >> 7;
  int bc = tid & 63,  bh = tid >> 6;

  for (int kt = 0; kt < Kdim; kt += TBK) {
#pragma unroll
    for (int q = 0; q < 4; q++) {
      int s = ah * 4 + q;
      float4 v = *(const float4*)&A[(size_t)(r0 + am) * lda + kt + s * 4];
      As[s * 4 + 0][am] = v.x; As[s * 4 + 1][am] = v.y;
      As[s * 4 + 2][am] = v.z; As[s * 4 + 3][am] = v.w;
    }
#pragma unroll
    for (int q = 0; q < 2; q++) {
      int s = bh * 2 + q;
      float4 v = *(const float4*)&B[(size_t)(c0 + bc) * ldb + kt + s * 4];
      Bs[s * 4 + 0][bc] = v.x; Bs[s * 4 + 1][bc] = v.y;
      Bs[s * 4 + 2][bc] = v.z; Bs[s * 4 + 3][bc] = v.w;
    }
    __syncthreads();
#pragma unroll
    for (int k = 0; k < TBK; k++) {
      float a[8], b[4];
      *(float4*)&a[0] = *(const float4*)&As[k][ty * 8];
      *(float4*)&a[4] = *(const float4*)&As[k][ty * 8 + 4];
      *(float4*)&b[0] = *(const float4*)&Bs[k][tx * 4];
#pragma unroll
      for (int r = 0; r < 8; r++)
#pragma unroll
        for (int c = 0; c < 4; c++) acc[r][c] += a[r] * b[c];
    }
    __syncthreads();
  }
#pragma unroll
  for (int r = 0; r < 8; r++) {
    float* cp = &C[(size_t)(r0 + ty * 8 + r) * ldc + c0 + tx * 4];
    if (SUB) {
      float4 o = *(const float4*)cp;
      o.x -= acc[r][0]; o.y -= acc[r][1]; o.z -= acc[r][2]; o.w -= acc[r][3];
      *(float4*)cp = o;
    } else {
      float4 o; o.x = acc[r][0]; o.y = acc[r][1]; o.z = acc[r][2]; o.w = acc[r][3];
      *(float4*)cp = o;
    }
  }
}

// ---------------- alpha = (L L^T)^{-1} y  (1 workgroup, blocked) ----------------
__global__ void __launch_bounds__(256) solve_alpha(const float* __restrict__ Lg,
                                                   const float* __restrict__ Wall,
                                                   const void* __restrict__ y,
                                                   float* __restrict__ alpha,
                                                   const int* __restrict__ flag) {
  __shared__ float z[NT];
  __shared__ float t[NB];
  __shared__ float red[256];
  int f32 = flag[0];
  int tid = threadIdx.x;
  int wv = tid >> 6, lane = tid & 63;
  // forward: L z = y
  for (int kb = 0; kb < NBLK; kb++) {
    int r0 = kb * NB;
    for (int i = wv; i < NB; i += 4) {
      const float* Lr = Lg + (size_t)(r0 + i) * NT;
      float acc = 0.f;
      for (int c = lane; c < r0; c += 64) acc += Lr[c] * z[c];
#pragma unroll
      for (int off = 32; off > 0; off >>= 1) acc += __shfl_down(acc, off, 64);
      if (lane == 0) t[i] = getel(y, r0 + i, f32) - acc;
    }
    __syncthreads();
    if (tid < NB) {
      const float* Wr = Wall + (size_t)kb * NB * NB + tid * NB;
      float acc = 0.f;
      for (int c = 0; c < NB; c++) acc += Wr[c] * t[c];
      z[r0 + tid] = acc;
    }
    __syncthreads();
  }
  // backward: L^T a = z (in place)
  for (int kb = NBLK - 1; kb >= 0; kb--) {
    int r0 = kb * NB;
    {
      int i = tid & 127, h = tid >> 7;
      float acc = 0.f;
      for (int r = r0 + NB + h; r < NT; r += 2)
        acc += Lg[(size_t)r * NT + r0 + i] * z[r];
      red[tid] = acc;
    }
    __syncthreads();
    if (tid < NB) t[tid] = z[r0 + tid] - (red[tid] + red[tid + 128]);
    __syncthreads();
    if (tid < NB) {
      const float* Wb = Wall + (size_t)kb * NB * NB;
      float acc = 0.f;
      for (int c = 0; c < NB; c++) acc += Wb[(size_t)c * NB + tid] * t[c];
      z[r0 + tid] = acc;
    }
    __syncthreads();
  }
  for (int i = tid; i < NT; i += 256) alpha[i] = z[i];
}

// mu = Ks^T alpha  (f32 out)
__global__ void mu_gemv(const float* __restrict__ Ks, const float* __restrict__ alpha,
                        float* __restrict__ mu) {
  int j = blockIdx.x * 256 + threadIdx.x;
  float s0 = 0.f, s1 = 0.f, s2 = 0.f, s3 = 0.f;
  for (int i = 0; i < NT; i += 4) {
    s0 += Ks[(size_t)i * MT + j]       * alpha[i];
    s1 += Ks[(size_t)(i + 1) * MT + j] * alpha[i + 1];
    s2 += Ks[(size_t)(i + 2) * MT + j] * alpha[i + 2];
    s3 += Ks[(size_t)(i + 3) * MT + j] * alpha[i + 3];
  }
  mu[j] = (s0 + s1) + (s2 + s3);
}

// ---------------- cov = Kss - v^T v (Kss fused; symmetric; f32 out) ----------------
__global__ void __launch_bounds__(256) cov_syrk(const float* __restrict__ V,
                                                const void* __restrict__ xs,
                                                const void* __restrict__ rls,
                                                const void* __restrict__ rvar,
                                                float* __restrict__ C,
                                                const int* __restrict__ flag) {
  int c0 = blockIdx.x * TBN;
  int r0 = blockIdx.y * TBM;
  if (r0 + TBM - 1 < c0) return;   // tile fully above diagonal: mirrors cover it
  __shared__ float As[TBK][TBM + 4];
  __shared__ float Bs[TBK][TBN + 4];
  int f32 = flag[0];
  int tid = threadIdx.x;
  int tx = tid & 15, ty = tid >> 4;
  float acc[8][4];
#pragma unroll
  for (int r = 0; r < 8; r++)
#pragma unroll
    for (int c = 0; c < 4; c++) acc[r][c] = 0.f;

  int ak = tid >> 5, am4 = (tid & 31) * 4;
  int bk = tid >> 4, bn4 = (tid & 15) * 4;

  for (int kt = 0; kt < NT; kt += TBK) {
#pragma unroll
    for (int p = 0; p < 4; p++) {
      int kk = ak + p * 8;
      *(float4*)&As[kk][am4] = *(const float4*)&V[(size_t)(kt + kk) * MT + r0 + am4];
    }
#pragma unroll
    for (int p = 0; p < 2; p++) {
      int kk = bk + p * 16;
      *(float4*)&Bs[kk][bn4] = *(const float4*)&V[(size_t)(kt + kk) * MT + c0 + bn4];
    }
    __syncthreads();
#pragma unroll
    for (int k = 0; k < TBK; k++) {
      float a[8], b[4];
      *(float4*)&a[0] = *(const float4*)&As[k][ty * 8];
      *(float4*)&a[4] = *(const float4*)&As[k][ty * 8 + 4];
      *(float4*)&b[0] = *(const float4*)&Bs[k][tx * 4];
#pragma unroll
      for (int r = 0; r < 8; r++)
#pragma unroll
        for (int c = 0; c < 4; c++) acc[r][c] += a[r] * b[c];
    }
    __syncthreads();
  }
  float ls  = softplusf(getsc(rls, f32));
  float var = softplusf(getsc(rvar, f32));
  float cc  = -0.5f / (ls * ls);
#pragma unroll
  for (int r = 0; r < 8; r++) {
    int row = r0 + ty * 8 + r;
    float xr[8];
    load_pt(xs, row, f32, xr);
    int colb = c0 + tx * 4;
#pragma unroll
    for (int c = 0; c < 4; c++) {
      int col = colb + c;
      float xc[8];
      load_pt(xs, col, f32, xc);
      float d = 0.f;
#pragma unroll
      for (int q = 0; q < 8; q++) { float tdf = xr[q] - xc[q]; d += tdf * tdf; }
      float kss = var * expf(cc * d);
      if (row == col) kss += 1e-6f;
      float ov = kss - acc[r][c];
      if (row >= col) C[(size_t)row * MT + col] = ov;   // lower + diag: direct
      if (row > col)  C[(size_t)col * MT + row] = ov;   // strict lower: mirror to upper
    }
  }
}

// ---------------- host ----------------
extern "C" void kernel_launch(void* const* d_in, const int* in_sizes, int n_in,
                              void* d_out, int out_size, void* d_ws, size_t ws_size,
                              hipStream_t stream) {
  (void)in_sizes; (void)n_in; (void)out_size; (void)ws_size;
  const void* xt  = d_in[0];
  const void* y   = d_in[1];
  const void* w   = d_in[2];
  const void* xs  = d_in[3];
  const void* rls = d_in[4];
  const void* rva = d_in[5];
  const void* rnv = d_in[6];

  float* mu_out  = (float*)d_out;        // [MT] f32
  float* cov_out = mu_out + MT;          // [MT*MT] f32

  float* Kf    = (float*)d_ws;                             // NT*NT
  float* Ks    = Kf + (size_t)NT * NT;                     // NT*MT (becomes v)
  float* Wall  = Ks + (size_t)NT * MT;                     // NBLK*NB*NB
  float* S     = Wall + (size_t)NBLK * NB * NB;            // (NT-NB)*NB panel scratch
  float* alpha = S + (size_t)(NT - NB) * NB;               // NT
  int*   flag  = (int*)(alpha + NT);                       // dtype flag

  detect_dtype<<<1, 64, 0, stream>>>((const unsigned short*)xt, flag);
  build_K<<<dim3(NT / 16, NT / 16), dim3(16, 16), 0, stream>>>(xt, w, rls, rva, rnv, Kf, flag);
  build_Ks<<<dim3(MT / 16, NT / 16), dim3(16, 16), 0, stream>>>(xt, xs, w, rls, rva, Ks, flag);

  // blocked Cholesky of Kf (lower), with explicit diag-block inverses
  for (int kb = 0; kb < NBLK; kb++) {
    potrf_diag<<<1, 256, 0, stream>>>(Kf, kb);
    invert_diag<<<1, 256, 0, stream>>>(Kf, Wall, kb);
    int t0 = (kb + 1) * NB;
    int rows = NT - t0;
    if (rows > 0) {
      copy_panel<<<(rows * NB) / 256, 256, 0, stream>>>(Kf, S, t0, rows, kb);
      // L21 = A21 @ W^T
      gemm_nt<0, 0><<<dim3(NB / TBN, rows / TBM), 256, 0, stream>>>(
          S, NB, Wall + (size_t)kb * NB * NB, NB,
          Kf + (size_t)t0 * NT + kb * NB, NT, NB);
      // A22 -= L21 @ L21^T (lower tiles only)
      gemm_nt<1, 1><<<dim3(rows / TBN, rows / TBM), 256, 0, stream>>>(
          Kf + (size_t)t0 * NT + kb * NB, NT,
          Kf + (size_t)t0 * NT + kb * NB, NT,
          Kf + (size_t)t0 * NT + t0, NT, NB);
    }
  }

  solve_alpha<<<1, 256, 0, stream>>>(Kf, Wall, y, alpha, flag);
  mu_gemv<<<MT / 256, 256, 0, stream>>>(Ks, alpha, mu_out);   // before Ks is overwritten

  // v = L^{-1} Ks, in place (right-looking blocked forward substitution)
  for (int kb = 0; kb < NBLK; kb++) {
    gemm_nn<0><<<dim3(MT / TBN, 1), 256, 0, stream>>>(
        Wall + (size_t)kb * NB * NB, NB,
        Ks + (size_t)kb * NB * MT, MT,
        Ks + (size_t)kb * NB * MT, MT, NB);
    int t0 = (kb + 1) * NB;
    int rows = NT - t0;
    if (rows > 0) {
      gemm_nn<1><<<dim3(MT / TBN, rows / TBM), 256, 0, stream>>>(
          Kf + (size_t)t0 * NT + kb * NB, NT,
          Ks + (size_t)kb * NB * MT, MT,
          Ks + (size_t)t0 * MT, MT, NB);
    }
  }

  cov_syrk<<<dim3(MT / TBN, MT / TBM), 256, 0, stream>>>(Ks, xs, rls, rva, cov_out, flag);
}

// Round 4
// 29178.809 us; speedup vs baseline: 1.6553x; 1.6553x over previous
//
#include <hip/hip_runtime.h>
#include <math.h>

#define NT 4096      // n_train
#define MT 8192      // n_test
#define NB 128       // cholesky block
#define NBLK 32      // NT/NB
#define TBM 128      // gemm tile M
#define TBN 64       // gemm tile N
#define TBK 32       // gemm tile K
#define SRPB 64      // solve: rows per update block

// ---------------- helpers ----------------
__device__ __forceinline__ float bf2f(unsigned short h) {
  return __uint_as_float(((unsigned)h) << 16);
}
__device__ __forceinline__ float softplusf(float x) { return log1pf(expf(x)); }

__device__ __forceinline__ void load8bf(const unsigned short* __restrict__ p, float* f) {
  ushort4 u0 = *(const ushort4*)p;
  ushort4 u1 = *(const ushort4*)(p + 4);
  f[0] = bf2f(u0.x); f[1] = bf2f(u0.y); f[2] = bf2f(u0.z); f[3] = bf2f(u0.w);
  f[4] = bf2f(u1.x); f[5] = bf2f(u1.y); f[6] = bf2f(u1.z); f[7] = bf2f(u1.w);
}

// dtype-polymorphic input readers (flag: 1 = f32 inputs, 0 = bf16 inputs)
__device__ __forceinline__ float getsc(const void* p, int f32) {
  return f32 ? *(const float*)p : bf2f(*(const unsigned short*)p);
}
__device__ __forceinline__ float getel(const void* p, int i, int f32) {
  return f32 ? ((const float*)p)[i] : bf2f(((const unsigned short*)p)[i]);
}
__device__ __forceinline__ void load_pt(const void* xb, int idx, int f32, float* f) {
  if (f32) {
    const float4* q = (const float4*)xb;
    float4 a = q[idx * 2], b = q[idx * 2 + 1];
    f[0] = a.x; f[1] = a.y; f[2] = a.z; f[3] = a.w;
    f[4] = b.x; f[5] = b.y; f[6] = b.z; f[7] = b.w;
  } else {
    load8bf((const unsigned short*)xb + idx * 8, f);
  }
}

// uniform-[0,1) bf16 ushorts are all < 0x4000; f32 low mantissa halves are ~random
__global__ void detect_dtype(const unsigned short* __restrict__ xt, int* __restrict__ flag) {
  if (threadIdx.x == 0) {
    int f = 0;
    for (int i = 0; i < 32; i++) if (xt[i] >= 0x4000) f = 1;
    flag[0] = f;
  }
}

// ---------------- kernel-matrix builders (-> f32 out) ----------------
__global__ void build_K(const void* __restrict__ xt, const void* __restrict__ w,
                        const void* __restrict__ rls, const void* __restrict__ rvar,
                        const void* __restrict__ rnv, float* __restrict__ K,
                        const int* __restrict__ flag) {
  int f32 = flag[0];
  int j = blockIdx.x * 16 + threadIdx.x;
  int i = blockIdx.y * 16 + threadIdx.y;
  float ls  = softplusf(getsc(rls, f32));
  float var = softplusf(getsc(rvar, f32));
  float cc  = -0.5f / (ls * ls);
  float v;
  if (i == j) {
    v = var + softplusf(getsc(rnv, f32)) + 1e-6f;      // rbf diag = var, + noise
  } else {
    float a[8], b[8];
    load_pt(xt, i, f32, a);
    load_pt(xt, j, f32, b);
    float d = 0.f;
#pragma unroll
    for (int q = 0; q < 8; q++) { float t = a[q] - b[q]; d += t * t; }
    v = var * expf(cc * d) * getel(w, i, f32) * getel(w, j, f32);
  }
  K[(size_t)i * NT + j] = v;
}

__global__ void build_Ks(const void* __restrict__ xt, const void* __restrict__ xs,
                         const void* __restrict__ w, const void* __restrict__ rls,
                         const void* __restrict__ rvar, float* __restrict__ Ks,
                         const int* __restrict__ flag) {
  int f32 = flag[0];
  int j = blockIdx.x * 16 + threadIdx.x;   // test
  int i = blockIdx.y * 16 + threadIdx.y;   // train
  float ls  = softplusf(getsc(rls, f32));
  float var = softplusf(getsc(rvar, f32));
  float cc  = -0.5f / (ls * ls);
  float a[8], b[8];
  load_pt(xt, i, f32, a);
  load_pt(xs, j, f32, b);
  float d = 0.f;
#pragma unroll
  for (int q = 0; q < 8; q++) { float t = a[q] - b[q]; d += t * t; }
  Ks[(size_t)i * MT + j] = getel(w, i, f32) * var * expf(cc * d);
}

// ---------------- fused diag-block Cholesky + inverse (1 WG, 128 KB LDS) ----------------
// At col-major raw outer-product form; Wv = Lkk^{-1} via elimination from LDS.
__global__ void __launch_bounds__(256) potrf_invert(float* __restrict__ Kg,
                                                    float* __restrict__ Wall, int kb) {
  __shared__ float At[NB * NB];   // 64 KB
  __shared__ float Wv[NB * NB];   // 64 KB
  int tid = threadIdx.x;
  int r0 = kb * NB;
  for (int idx = tid; idx < NB * NB; idx += 256) {
    int k = idx >> 7, i = idx & 127;
    At[idx] = Kg[(size_t)(r0 + k) * NT + r0 + i];   // symmetric block: coalesced
    Wv[idx] = (k == i) ? 1.f : 0.f;
  }
  __syncthreads();
  // raw cholesky: d_j stays on diag, multipliers raw
  for (int j = 0; j < NB; j++) {
    float inv = 1.0f / At[j * NB + j];
    int nel = (NB - 1 - j) << 7;
    for (int idx = tid; idx < nel; idx += 256) {
      int k = j + 1 + (idx >> 7);
      int i = idx & 127;
      if (i >= k) At[k * NB + i] -= At[j * NB + i] * (At[j * NB + k] * inv);
    }
    __syncthreads();
  }
  // forward elimination of I: factor L[i,t]/L[t,t] = Raw[i,t]/d_t
  for (int t = 0; t < NB; t++) {
    float invd = 1.0f / At[t * NB + t];
    int nel = (NB - 1 - t) << 7;
    for (int idx = tid; idx < nel; idx += 256) {
      int i = t + 1 + (idx >> 7);
      int c = idx & 127;
      Wv[i * NB + c] -= (At[t * NB + i] * invd) * Wv[t * NB + c];
    }
    __syncthreads();
  }
  // write back true L (scaled) and W (rows scaled by 1/L[i,i])
  for (int idx = tid; idx < NB * NB; idx += 256) {
    int k = idx >> 7, i = idx & 127;
    if (i >= k) {
      float s = sqrtf(At[k * NB + k]);
      Kg[(size_t)(r0 + i) * NT + r0 + k] = (i == k) ? s : At[idx] / s;
    }
  }
  float* Wg = Wall + (size_t)kb * NB * NB;
  for (int idx = tid; idx < NB * NB; idx += 256) {
    int i = idx >> 7;
    Wg[idx] = Wv[idx] / sqrtf(At[i * NB + i]);
  }
}

__global__ void copy_panel(const float* __restrict__ Kg, float* __restrict__ S,
                           int t0, int rows, int kb) {
  int idx = blockIdx.x * 256 + threadIdx.x;
  if (idx < rows * NB) {
    int r = idx >> 7, c = idx & 127;
    S[idx] = Kg[(size_t)(t0 + r) * NT + kb * NB + c];
  }
}

// ---------------- f32 GEMM tiles: 128x64x32, 256 thr, 8x4 regs ----------------
template<int SUB>
__global__ void __launch_bounds__(256) gemm_nn(const float* __restrict__ A, int lda,
                                               const float* __restrict__ B, int ldb,
                                               float* __restrict__ C, int ldc, int Kdim) {
  __shared__ float As[TBK][TBM + 4];
  __shared__ float Bs[TBK][TBN + 4];
  int tid = threadIdx.x;
  int c0 = blockIdx.x * TBN;
  int r0 = blockIdx.y * TBM;
  int tx = tid & 15, ty = tid >> 4;
  float acc[8][4];
#pragma unroll
  for (int r = 0; r < 8; r++)
#pragma unroll
    for (int c = 0; c < 4; c++) acc[r][c] = 0.f;

  int am = tid & 127, ah = tid >> 7;
  int bn = tid & 15,  bk = tid >> 4;

  for (int kt = 0; kt < Kdim; kt += TBK) {
#pragma unroll
    for (int q = 0; q < 4; q++) {
      int s = ah * 4 + q;
      float4 v = *(const float4*)&A[(size_t)(r0 + am) * lda + kt + s * 4];
      As[s * 4 + 0][am] = v.x; As[s * 4 + 1][am] = v.y;
      As[s * 4 + 2][am] = v.z; As[s * 4 + 3][am] = v.w;
    }
#pragma unroll
    for (int p = 0; p < 2; p++) {
      int kk = bk + p * 16;
      *(float4*)&Bs[kk][bn * 4] = *(const float4*)&B[(size_t)(kt + kk) * ldb + c0 + bn * 4];
    }
    __syncthreads();
#pragma unroll
    for (int k = 0; k < TBK; k++) {
      float a[8], b[4];
      *(float4*)&a[0] = *(const float4*)&As[k][ty * 8];
      *(float4*)&a[4] = *(const float4*)&As[k][ty * 8 + 4];
      *(float4*)&b[0] = *(const float4*)&Bs[k][tx * 4];
#pragma unroll
      for (int r = 0; r < 8; r++)
#pragma unroll
        for (int c = 0; c < 4; c++) acc[r][c] += a[r] * b[c];
    }
    __syncthreads();
  }
#pragma unroll
  for (int r = 0; r < 8; r++) {
    float* cp = &C[(size_t)(r0 + ty * 8 + r) * ldc + c0 + tx * 4];
    if (SUB) {
      float4 o = *(const float4*)cp;
      o.x -= acc[r][0]; o.y -= acc[r][1]; o.z -= acc[r][2]; o.w -= acc[r][3];
      *(float4*)cp = o;
    } else {
      float4 o; o.x = acc[r][0]; o.y = acc[r][1]; o.z = acc[r][2]; o.w = acc[r][3];
      *(float4*)cp = o;
    }
  }
}

// NT: C (op)= A[M x K] @ B[N x K]^T  (SYRK=1: skip tiles fully above diagonal)
template<int SUB, int SYRK>
__global__ void __launch_bounds__(256) gemm_nt(const float* __restrict__ A, int lda,
                                               const float* __restrict__ B, int ldb,
                                               float* __restrict__ C, int ldc, int Kdim) {
  int c0 = blockIdx.x * TBN;
  int r0 = blockIdx.y * TBM;
  if (SYRK && c0 > r0 + TBM - 1) return;
  __shared__ float As[TBK][TBM + 4];
  __shared__ float Bs[TBK][TBN + 4];
  int tid = threadIdx.x;
  int tx = tid & 15, ty = tid >> 4;
  float acc[8][4];
#pragma unroll
  for (int r = 0; r < 8; r++)
#pragma unroll
    for (int c = 0; c < 4; c++) acc[r][c] = 0.f;

  int am = tid & 127, ah = tid >> 7;
  int bc = tid & 63,  bh = tid >> 6;

  for (int kt = 0; kt < Kdim; kt += TBK) {
#pragma unroll
    for (int q = 0; q < 4; q++) {
      int s = ah * 4 + q;
      float4 v = *(const float4*)&A[(size_t)(r0 + am) * lda + kt + s * 4];
      As[s * 4 + 0][am] = v.x; As[s * 4 + 1][am] = v.y;
      As[s * 4 + 2][am] = v.z; As[s * 4 + 3][am] = v.w;
    }
#pragma unroll
    for (int q = 0; q < 2; q++) {
      int s = bh * 2 + q;
      float4 v = *(const float4*)&B[(size_t)(c0 + bc) * ldb + kt + s * 4];
      Bs[s * 4 + 0][bc] = v.x; Bs[s * 4 + 1][bc] = v.y;
      Bs[s * 4 + 2][bc] = v.z; Bs[s * 4 + 3][bc] = v.w;
    }
    __syncthreads();
#pragma unroll
    for (int k = 0; k < TBK; k++) {
      float a[8], b[4];
      *(float4*)&a[0] = *(const float4*)&As[k][ty * 8];
      *(float4*)&a[4] = *(const float4*)&As[k][ty * 8 + 4];
      *(float4*)&b[0] = *(const float4*)&Bs[k][tx * 4];
#pragma unroll
      for (int r = 0; r < 8; r++)
#pragma unroll
        for (int c = 0; c < 4; c++) acc[r][c] += a[r] * b[c];
    }
    __syncthreads();
  }
#pragma unroll
  for (int r = 0; r < 8; r++) {
    float* cp = &C[(size_t)(r0 + ty * 8 + r) * ldc + c0 + tx * 4];
    if (SUB) {
      float4 o = *(const float4*)cp;
      o.x -= acc[r][0]; o.y -= acc[r][1]; o.z -= acc[r][2]; o.w -= acc[r][3];
      *(float4*)cp = o;
    } else {
      float4 o; o.x = acc[r][0]; o.y = acc[r][1]; o.z = acc[r][2]; o.w = acc[r][3];
      *(float4*)cp = o;
    }
  }
}

// ---------------- multi-WG blocked triangular solves for alpha ----------------
__global__ void init_r(const void* __restrict__ y, float* __restrict__ r,
                       const int* __restrict__ flag) {
  int i = blockIdx.x * 256 + threadIdx.x;
  r[i] = getel(y, i, flag[0]);
}

// forward step kb: every block computes t = W_kb * r[kb-block] (redundant, L2-hit);
// block 0 writes z[kb-block]=t; blocks 1+ update r rows below via coalesced panel GEMV.
__global__ void __launch_bounds__(256) fwd_step(const float* __restrict__ Lg,
                                                const float* __restrict__ Wall,
                                                float* __restrict__ r,
                                                float* __restrict__ z, int kb) {
  __shared__ float ts[NB];
  __shared__ float part[256];
  int tid = threadIdx.x;
  int r0 = kb * NB;
  {
    int row = tid >> 1, half = tid & 1;
    const float* Wr = Wall + (size_t)kb * NB * NB + row * NB + half * 64;
    const float* rv = r + r0 + half * 64;
    float acc = 0.f;
#pragma unroll
    for (int c = 0; c < 64; c += 4) {
      float4 wv = *(const float4*)&Wr[c];
      float4 xv = *(const float4*)&rv[c];
      acc += wv.x * xv.x + wv.y * xv.y + wv.z * xv.z + wv.w * xv.w;
    }
    part[tid] = acc;
    __syncthreads();
    if (half == 0) ts[row] = part[tid] + part[tid + 1];
    __syncthreads();
  }
  if (blockIdx.x == 0) {
    if (tid < NB) z[r0 + tid] = ts[tid];
    return;
  }
  int base = r0 + NB + (blockIdx.x - 1) * SRPB;
  int wv_ = tid >> 6, lane = tid & 63;
  for (int rr = wv_; rr < SRPB; rr += 4) {
    int row = base + rr;
    const float* Lr = Lg + (size_t)row * NT + r0;
    float acc = Lr[lane] * ts[lane] + Lr[lane + 64] * ts[lane + 64];
#pragma unroll
    for (int off = 32; off > 0; off >>= 1) acc += __shfl_down(acc, off, 64);
    if (lane == 0) r[row] -= acc;
  }
}

// backward step kb: every block computes t = W_kb^T * z[kb-block]; block 0 writes
// a[kb-block]=t; blocks 1+ update z[cb-block] (cb<kb) via transposed panel GEMV.
__global__ void __launch_bounds__(256) bwd_step(const float* __restrict__ Lg,
                                                const float* __restrict__ Wall,
                                                float* __restrict__ z,
                                                float* __restrict__ a, int kb) {
  __shared__ float ts[NB];
  __shared__ float part[256];
  int tid = threadIdx.x;
  int r0 = kb * NB;
  {
    int col = tid & 127, half = tid >> 7;
    const float* Wb = Wall + (size_t)kb * NB * NB;
    float acc = 0.f;
#pragma unroll 4
    for (int rr = half * 64; rr < half * 64 + 64; rr++)
      acc += Wb[rr * NB + col] * z[r0 + rr];
    part[tid] = acc;
    __syncthreads();
    if (half == 0) ts[col] = part[tid] + part[tid + 128];
    __syncthreads();
  }
  if (blockIdx.x == 0) {
    if (tid < NB) a[r0 + tid] = ts[tid];
    return;
  }
  int cb = blockIdx.x - 1;
  int col = cb * NB + (tid & 127);
  int half = tid >> 7;
  float acc = 0.f;
#pragma unroll 4
  for (int jr = half * 64; jr < half * 64 + 64; jr++)
    acc += Lg[(size_t)(r0 + jr) * NT + col] * ts[jr];
  part[tid] = acc;
  __syncthreads();
  if (half == 0) z[col] -= part[tid] + part[tid + 128];
}

// ---------------- mu = Ks^T alpha (K-split + atomics) ----------------
__global__ void zero_mu(float* __restrict__ mu) {
  mu[blockIdx.x * 256 + threadIdx.x] = 0.f;
}
__global__ void mu_gemv(const float* __restrict__ Ks, const float* __restrict__ alpha,
                        float* __restrict__ mu) {
  int j = blockIdx.x * 256 + threadIdx.x;
  int k0 = blockIdx.y * (NT / 16);
  float s0 = 0.f, s1 = 0.f;
  for (int i = k0; i < k0 + NT / 16; i += 2) {
    s0 += Ks[(size_t)i * MT + j] * alpha[i];
    s1 += Ks[(size_t)(i + 1) * MT + j] * alpha[i + 1];
  }
  atomicAdd(&mu[j], s0 + s1);
}

// ---------------- cov = Kss - v^T v (Kss fused; symmetric; f32 out) ----------------
__global__ void __launch_bounds__(256) cov_syrk(const float* __restrict__ V,
                                                const void* __restrict__ xs,
                                                const void* __restrict__ rls,
                                                const void* __restrict__ rvar,
                                                float* __restrict__ C,
                                                const int* __restrict__ flag) {
  int c0 = blockIdx.x * TBN;
  int r0 = blockIdx.y * TBM;
  if (r0 + TBM - 1 < c0) return;   // tile fully above diagonal: mirrors cover it
  __shared__ float As[TBK][TBM + 4];
  __shared__ float Bs[TBK][TBN + 4];
  int f32 = flag[0];
  int tid = threadIdx.x;
  int tx = tid & 15, ty = tid >> 4;
  float acc[8][4];
#pragma unroll
  for (int r = 0; r < 8; r++)
#pragma unroll
    for (int c = 0; c < 4; c++) acc[r][c] = 0.f;

  int ak = tid >> 5, am4 = (tid & 31) * 4;
  int bk = tid >> 4, bn4 = (tid & 15) * 4;

  for (int kt = 0; kt < NT; kt += TBK) {
#pragma unroll
    for (int p = 0; p < 4; p++) {
      int kk = ak + p * 8;
      *(float4*)&As[kk][am4] = *(const float4*)&V[(size_t)(kt + kk) * MT + r0 + am4];
    }
#pragma unroll
    for (int p = 0; p < 2; p++) {
      int kk = bk + p * 16;
      *(float4*)&Bs[kk][bn4] = *(const float4*)&V[(size_t)(kt + kk) * MT + c0 + bn4];
    }
    __syncthreads();
#pragma unroll
    for (int k = 0; k < TBK; k++) {
      float a[8], b[4];
      *(float4*)&a[0] = *(const float4*)&As[k][ty * 8];
      *(float4*)&a[4] = *(const float4*)&As[k][ty * 8 + 4];
      *(float4*)&b[0] = *(const float4*)&Bs[k][tx * 4];
#pragma unroll
      for (int r = 0; r < 8; r++)
#pragma unroll
        for (int c = 0; c < 4; c++) acc[r][c] += a[r] * b[c];
    }
    __syncthreads();
  }
  float ls  = softplusf(getsc(rls, f32));
  float var = softplusf(getsc(rvar, f32));
  float cc  = -0.5f / (ls * ls);
#pragma unroll
  for (int r = 0; r < 8; r++) {
    int row = r0 + ty * 8 + r;
    float xr[8];
    load_pt(xs, row, f32, xr);
    int colb = c0 + tx * 4;
#pragma unroll
    for (int c = 0; c < 4; c++) {
      int col = colb + c;
      float xc[8];
      load_pt(xs, col, f32, xc);
      float d = 0.f;
#pragma unroll
      for (int q = 0; q < 8; q++) { float tdf = xr[q] - xc[q]; d += tdf * tdf; }
      float kss = var * expf(cc * d);
      if (row == col) kss += 1e-6f;
      float ov = kss - acc[r][c];
      if (row >= col) C[(size_t)row * MT + col] = ov;   // lower + diag: direct
      if (row > col)  C[(size_t)col * MT + row] = ov;   // strict lower: mirror to upper
    }
  }
}

// ---------------- host ----------------
extern "C" void kernel_launch(void* const* d_in, const int* in_sizes, int n_in,
                              void* d_out, int out_size, void* d_ws, size_t ws_size,
                              hipStream_t stream) {
  (void)in_sizes; (void)n_in; (void)out_size; (void)ws_size;
  const void* xt  = d_in[0];
  const void* y   = d_in[1];
  const void* w   = d_in[2];
  const void* xs  = d_in[3];
  const void* rls = d_in[4];
  const void* rva = d_in[5];
  const void* rnv = d_in[6];

  float* mu_out  = (float*)d_out;        // [MT] f32
  float* cov_out = mu_out + MT;          // [MT*MT] f32

  float* Kf    = (float*)d_ws;                             // NT*NT
  float* Ks    = Kf + (size_t)NT * NT;                     // NT*MT (becomes v)
  float* Wall  = Ks + (size_t)NT * MT;                     // NBLK*NB*NB
  float* S     = Wall + (size_t)NBLK * NB * NB;            // (NT-NB)*NB panel scratch
  float* rbuf  = S + (size_t)(NT - NB) * NB;               // NT (fwd residual)
  float* zbuf  = rbuf + NT;                                // NT (fwd solution / bwd residual)
  float* abuf  = zbuf + NT;                                // NT (alpha)
  int*   flag  = (int*)(abuf + NT);                        // dtype flag

  detect_dtype<<<1, 64, 0, stream>>>((const unsigned short*)xt, flag);
  build_K<<<dim3(NT / 16, NT / 16), dim3(16, 16), 0, stream>>>(xt, w, rls, rva, rnv, Kf, flag);
  build_Ks<<<dim3(MT / 16, NT / 16), dim3(16, 16), 0, stream>>>(xt, xs, w, rls, rva, Ks, flag);

  // blocked Cholesky of Kf (lower), with explicit diag-block inverses
  for (int kb = 0; kb < NBLK; kb++) {
    potrf_invert<<<1, 256, 0, stream>>>(Kf, Wall, kb);
    int t0 = (kb + 1) * NB;
    int rows = NT - t0;
    if (rows > 0) {
      copy_panel<<<(rows * NB) / 256, 256, 0, stream>>>(Kf, S, t0, rows, kb);
      // L21 = A21 @ W^T
      gemm_nt<0, 0><<<dim3(NB / TBN, rows / TBM), 256, 0, stream>>>(
          S, NB, Wall + (size_t)kb * NB * NB, NB,
          Kf + (size_t)t0 * NT + kb * NB, NT, NB);
      // A22 -= L21 @ L21^T (lower tiles only)
      gemm_nt<1, 1><<<dim3(rows / TBN, rows / TBM), 256, 0, stream>>>(
          Kf + (size_t)t0 * NT + kb * NB, NT,
          Kf + (size_t)t0 * NT + kb * NB, NT,
          Kf + (size_t)t0 * NT + t0, NT, NB);
    }
  }

  // alpha = (L L^T)^{-1} y via 64 small multi-WG dispatches
  init_r<<<NT / 256, 256, 0, stream>>>(y, rbuf, flag);
  for (int kb = 0; kb < NBLK; kb++) {
    int nupd = (NT - (kb + 1) * NB) / SRPB;
    fwd_step<<<1 + nupd, 256, 0, stream>>>(Kf, Wall, rbuf, zbuf, kb);
  }
  for (int kb = NBLK - 1; kb >= 0; kb--) {
    bwd_step<<<1 + kb, 256, 0, stream>>>(Kf, Wall, zbuf, abuf, kb);
  }

  zero_mu<<<MT / 256, 256, 0, stream>>>(mu_out);
  mu_gemv<<<dim3(MT / 256, 16), 256, 0, stream>>>(Ks, abuf, mu_out);  // before Ks overwritten

  // v = L^{-1} Ks, in place (right-looking blocked forward substitution)
  for (int kb = 0; kb < NBLK; kb++) {
    gemm_nn<0><<<dim3(MT / TBN, 1), 256, 0, stream>>>(
        Wall + (size_t)kb * NB * NB, NB,
        Ks + (size_t)kb * NB * MT, MT,
        Ks + (size_t)kb * NB * MT, MT, NB);
    int t0 = (kb + 1) * NB;
    int rows = NT - t0;
    if (rows > 0) {
      gemm_nn<1><<<dim3(MT / TBN, rows / TBM), 256, 0, stream>>>(
          Kf + (size_t)t0 * NT + kb * NB, NT,
          Ks + (size_t)kb * NB * MT, MT,
          Ks + (size_t)t0 * MT, MT, NB);
    }
  }

  cov_syrk<<<dim3(MT / TBN, MT / TBM), 256, 0, stream>>>(Ks, xs, rls, rva, cov_out, flag);
}